// Round 9
// baseline (461.766 us; speedup 1.0000x reference)
//
#include <hip/hip_runtime.h>
#include <hip/hip_fp16.h>

#define NN 100000     // num nodes
#define NE 1600000    // num edges
#define NEL 200000    // link-pred edges
#define NB 391        // (NN+255)/256 scan blocks
#define TM 64         // nodes per block in k_hw1
#define TM2 128       // nodes per block in k_hw2
#define RNG (NN / 8)  // 12500 dst-nodes per XCD partition

// ---------------- CSR build ----------------
__global__ void k_zero(int* __restrict__ c) {
    int i = blockIdx.x * blockDim.x + threadIdx.x;
    if (i < NN) c[i] = 0;
}

// Partitioned histogram: group g = blockIdx&7 (XCD swizzle heuristic) counts
// only dst in [g*RNG,(g+1)*RNG) -> atomics stay in one XCD's L2 slice.
__global__ __launch_bounds__(256) void k_hist(const int* __restrict__ dst,
                                              int* __restrict__ c) {
    int g  = blockIdx.x & 7;
    int kg = blockIdx.x >> 3;
    int lo = g * RNG, hi = lo + RNG;
    int stride = (gridDim.x >> 3) * 256;
    for (int e = kg * 256 + threadIdx.x; e < NE; e += stride) {
        int d = dst[e];
        if (d >= lo && d < hi) atomicAdd(&c[d], 1);
    }
}

__global__ void k_dinv(const int* __restrict__ c, float* __restrict__ dinv) {
    int i = blockIdx.x * blockDim.x + threadIdx.x;
    if (i < NN) dinv[i] = rsqrtf((float)(c[i] + 1));   // +1 self-loop
}

__global__ void k_bsum(const int* __restrict__ c, int* __restrict__ bsum) {
    __shared__ int s[256];
    int t = threadIdx.x, i = blockIdx.x * 256 + t;
    s[t] = (i < NN) ? c[i] : 0;
    __syncthreads();
    for (int st = 128; st > 0; st >>= 1) {
        if (t < st) s[t] += s[t + st];
        __syncthreads();
    }
    if (t == 0) bsum[blockIdx.x] = s[0];
}

__global__ void k_bscan(const int* __restrict__ bsum, int* __restrict__ ebsum) {
    __shared__ int s[512];
    int t = threadIdx.x;
    int v = (t < NB) ? bsum[t] : 0;
    s[t] = v;
    __syncthreads();
    for (int st = 1; st < 512; st <<= 1) {
        int tmp = (t >= st) ? s[t - st] : 0;
        __syncthreads();
        s[t] += tmp;
        __syncthreads();
    }
    if (t < NB) ebsum[t] = s[t] - v;   // exclusive
}

__global__ void k_offsets(int* __restrict__ c, const int* __restrict__ ebsum) {
    __shared__ int s[256];
    int t = threadIdx.x, i = blockIdx.x * 256 + t;
    int v = (i < NN) ? c[i] : 0;
    s[t] = v;
    __syncthreads();
    for (int st = 1; st < 256; st <<= 1) {
        int tmp = (t >= st) ? s[t - st] : 0;
        __syncthreads();
        s[t] += tmp;
        __syncthreads();
    }
    if (i < NN) c[i] = ebsum[blockIdx.x] + s[t] - v;   // exclusive offsets (in place)
}

// Partitioned fill; writes 8B records {src, dinv[src]} so the gather kernels
// need ZERO cross-lane ops per edge (R7 post-mortem: the LDS pipe was ~67%
// busy on __shfl broadcasts — that was the invariant ceiling R5-R7 all hit).
__global__ __launch_bounds__(256) void k_fill(const int* __restrict__ src,
                                              const int* __restrict__ dst,
                                              const float* __restrict__ dinv,
                                              int* __restrict__ off,
                                              int2* __restrict__ esrc) {
    int g  = blockIdx.x & 7;
    int kg = blockIdx.x >> 3;
    int lo = g * RNG, hi = lo + RNG;
    int stride = (gridDim.x >> 3) * 256;
    for (int e = kg * 256 + threadIdx.x; e < NE; e += stride) {
        int d = dst[e];
        if (d >= lo && d < hi) {
            int s = src[e];
            int p = atomicAdd(&off[d], 1);
            esrc[p] = make_int2(s, __float_as_int(dinv[s]));
        }
    }
    // post-fill: off[d] == end of row d; row d = [off[d-1], off[d]), off[-1]=0
}

// ---------------- hw1 = [x | pos] @ W1  (80 -> 64), tiled GEMM, fp16 out ---
__global__ __launch_bounds__(256) void k_hw1(const float* __restrict__ x,
                                             const float* __restrict__ pos,
                                             const float* __restrict__ W1,
                                             __half* __restrict__ hw1) {
    __shared__ float sh[TM * 80];   // [node][feat 0..79]
    __shared__ float sw[80 * 64];   // [k][j]
    int tid = threadIdx.x;
    for (int t = tid; t < 80 * 64; t += 256) sw[t] = W1[t];
    int nb = blockIdx.x * TM;
    for (int i = tid; i < TM * 64; i += 256) {       // x part (coalesced)
        int node = i >> 6, ch = i & 63;
        int g = nb + node;
        sh[node * 80 + ch] = (g < NN) ? x[g * 64 + ch] : 0.0f;
    }
    for (int i = tid; i < TM * 16; i += 256) {       // pos part (coalesced)
        int node = i >> 4, ch = i & 15;
        int g = nb + node;
        sh[node * 80 + 64 + ch] = (g < NN) ? pos[g * 16 + ch] : 0.0f;
    }
    __syncthreads();
    int j  = (tid & 15) * 4;        // output channel base
    int nl = (tid >> 4) * 4;        // local node base
    float a00=0,a01=0,a02=0,a03=0, a10=0,a11=0,a12=0,a13=0;
    float a20=0,a21=0,a22=0,a23=0, a30=0,a31=0,a32=0,a33=0;
#pragma unroll 4
    for (int k = 0; k < 80; ++k) {
        float4 wv = *(const float4*)&sw[k * 64 + j];
        float h0 = sh[(nl + 0) * 80 + k];
        float h1 = sh[(nl + 1) * 80 + k];
        float h2 = sh[(nl + 2) * 80 + k];
        float h3 = sh[(nl + 3) * 80 + k];
        a00 += h0 * wv.x; a01 += h0 * wv.y; a02 += h0 * wv.z; a03 += h0 * wv.w;
        a10 += h1 * wv.x; a11 += h1 * wv.y; a12 += h1 * wv.z; a13 += h1 * wv.w;
        a20 += h2 * wv.x; a21 += h2 * wv.y; a22 += h2 * wv.z; a23 += h2 * wv.w;
        a30 += h3 * wv.x; a31 += h3 * wv.y; a32 += h3 * wv.z; a33 += h3 * wv.w;
    }
    int g0 = nb + nl;
    union { __half2 h2v[2]; float2 f2; } u;
#define STORE_ROW(r, b0, b1, b2, b3)                                          \
    if (g0 + r < NN) {                                                        \
        u.h2v[0] = __floats2half2_rn(b0, b1);                                 \
        u.h2v[1] = __floats2half2_rn(b2, b3);                                 \
        *(float2*)&hw1[(g0 + r) * 64 + j] = u.f2;                             \
    }
    STORE_ROW(0, a00, a01, a02, a03)
    STORE_ROW(1, a10, a11, a12, a13)
    STORE_ROW(2, a20, a21, a22, a23)
    STORE_ROW(3, a30, a31, a32, a33)
#undef STORE_ROW
}

// ---------------- layer-1 gather (shuffle-free) ----------------------------
// h2[d][c] = relu(b1[c] + sum_e hw1[s]*dinv[s]*dinv[d] + hw1[d]*dinv[d]^2)
// Per edge: one wave-uniform 8B broadcast load of {s, dinv[s]} + one gather.
// NO LDS, NO __shfl, NO __syncthreads. 4-deep unroll for MLP.
__global__ __launch_bounds__(256) void k_gather1(const int* __restrict__ off,
                                                 const int2* __restrict__ esrc,
                                                 const float* __restrict__ dinv,
                                                 const __half* __restrict__ hw,
                                                 const float* __restrict__ b1,
                                                 __half* __restrict__ h2out) {
    int lane = threadIdx.x & 63;
    int wave = threadIdx.x >> 6;
    int d = blockIdx.x * 4 + wave;             // grid = NN/4 exactly
    int start = (d == 0) ? 0 : off[d - 1];
    int end = off[d];
    float dd = dinv[d];
    float hself = __half2float(hw[d * 64 + lane]);   // hoisted: overlaps loop
    float acc0 = 0.0f, acc1 = 0.0f, acc2 = 0.0f, acc3 = 0.0f;
    int e = start;
    for (; e + 3 < end; e += 4) {              // 4 outstanding gathers
        int2 r0 = esrc[e];
        int2 r1 = esrc[e + 1];
        int2 r2 = esrc[e + 2];
        int2 r3 = esrc[e + 3];
        acc0 += __half2float(hw[r0.x * 64 + lane]) * (__int_as_float(r0.y) * dd);
        acc1 += __half2float(hw[r1.x * 64 + lane]) * (__int_as_float(r1.y) * dd);
        acc2 += __half2float(hw[r2.x * 64 + lane]) * (__int_as_float(r2.y) * dd);
        acc3 += __half2float(hw[r3.x * 64 + lane]) * (__int_as_float(r3.y) * dd);
    }
    for (; e < end; ++e) {                     // uniform remainder
        int2 r0 = esrc[e];
        acc0 += __half2float(hw[r0.x * 64 + lane]) * (__int_as_float(r0.y) * dd);
    }
    float v = fmaxf(b1[lane] + ((acc0 + acc1) + (acc2 + acc3) + hself * dd * dd), 0.0f);
    h2out[d * 64 + lane] = __float2half_rn(v);
}

// ---------------- hw2 = h2 @ W2  (64 -> 32), tiled GEMM, fp16 in/out -------
// Replaces the in-wave shuffle epilogue of the old fused gather (33 LDS-pipe
// ops per row). LDS h-tile padded to stride 65 to break same-bank broadcast.
__global__ __launch_bounds__(256) void k_hw2(const __half* __restrict__ h2,
                                             const float* __restrict__ W2,
                                             __half* __restrict__ hw2) {
    __shared__ float sh[TM2 * 65];  // [node][feat], stride 65 (pad)
    __shared__ float sw[64 * 32];   // [k][j]
    int tid = threadIdx.x;
    for (int t = tid; t < 64 * 32; t += 256) sw[t] = W2[t];
    int nb = blockIdx.x * TM2;
    for (int i = tid; i < TM2 * 64; i += 256) {      // coalesced 2B loads
        int node = i >> 6, ch = i & 63;
        int g = nb + node;
        sh[node * 65 + ch] = (g < NN) ? __half2float(h2[g * 64 + ch]) : 0.0f;
    }
    __syncthreads();
    int j  = (tid & 7) * 4;         // output channel base (32 ch -> 8 groups)
    int nl = (tid >> 3) * 4;        // local node base (128 nodes -> 32 groups)
    float a00=0,a01=0,a02=0,a03=0, a10=0,a11=0,a12=0,a13=0;
    float a20=0,a21=0,a22=0,a23=0, a30=0,a31=0,a32=0,a33=0;
#pragma unroll 4
    for (int k = 0; k < 64; ++k) {
        float4 wv = *(const float4*)&sw[k * 32 + j];
        float h0 = sh[(nl + 0) * 65 + k];
        float h1 = sh[(nl + 1) * 65 + k];
        float h2v = sh[(nl + 2) * 65 + k];
        float h3 = sh[(nl + 3) * 65 + k];
        a00 += h0 * wv.x;  a01 += h0 * wv.y;  a02 += h0 * wv.z;  a03 += h0 * wv.w;
        a10 += h1 * wv.x;  a11 += h1 * wv.y;  a12 += h1 * wv.z;  a13 += h1 * wv.w;
        a20 += h2v * wv.x; a21 += h2v * wv.y; a22 += h2v * wv.z; a23 += h2v * wv.w;
        a30 += h3 * wv.x;  a31 += h3 * wv.y;  a32 += h3 * wv.z;  a33 += h3 * wv.w;
    }
    int g0 = nb + nl;
    union { __half2 h2v2[2]; float2 f2; } u;
#define STORE_ROW(r, b0, b1, b2, b3)                                          \
    if (g0 + r < NN) {                                                        \
        u.h2v2[0] = __floats2half2_rn(b0, b1);                                \
        u.h2v2[1] = __floats2half2_rn(b2, b3);                                \
        *(float2*)&hw2[(g0 + r) * 32 + j] = u.f2;                             \
    }
    STORE_ROW(0, a00, a01, a02, a03)
    STORE_ROW(1, a10, a11, a12, a13)
    STORE_ROW(2, a20, a21, a22, a23)
    STORE_ROW(3, a30, a31, a32, a33)
#undef STORE_ROW
}

// ---------------- layer-2 gather (C=32, shuffle-free edge loop) ------------
// z[d][j] = b2[j] + sum_e hw2[s]*dinv[s]*dinv[d] + hw2[d]*dinv[d]^2
// Half h takes edges start+h, start+h+2, ...; per half one 8B broadcast load
// per edge + gather; 2 accs/half = 4 outstanding. Divergent remainder is
// safe (no cross-lane ops inside); the single half-combine __shfl runs at
// full reconvergence.
__global__ __launch_bounds__(256) void k_gather2(const int* __restrict__ off,
                                                 const int2* __restrict__ esrc,
                                                 const float* __restrict__ dinv,
                                                 const __half* __restrict__ hw,
                                                 const float* __restrict__ b2,
                                                 float* __restrict__ outz) {
    int lane = threadIdx.x & 63;
    int half = lane >> 5;
    int j = lane & 31;
    int wave = threadIdx.x >> 6;
    int d = blockIdx.x * 4 + wave;             // grid = NN/4 exactly
    int start = (d == 0) ? 0 : off[d - 1];
    int end = off[d];
    float dd = dinv[d];
    float hself = __half2float(hw[d * 32 + j]);      // hoisted
    float accA = 0.0f, accB = 0.0f;
    int e = start;
    for (; e + 3 < end; e += 4) {
        int2 ra = esrc[e + half];
        int2 rb = esrc[e + half + 2];
        accA += __half2float(hw[ra.x * 32 + j]) * (__int_as_float(ra.y) * dd);
        accB += __half2float(hw[rb.x * 32 + j]) * (__int_as_float(rb.y) * dd);
    }
    for (int ee = e + half; ee < end; ee += 2) {     // divergent-safe tail
        int2 r = esrc[ee];
        accA += __half2float(hw[r.x * 32 + j]) * (__int_as_float(r.y) * dd);
    }
    float acc = accA + accB;
    acc += __shfl(acc, lane ^ 32, 64);         // combine halves (full exec)
    if (half == 0)
        outz[d * 32 + j] = b2[j] + (acc + hself * dd * dd);
}

// ---------------- link prediction head ----------------
__global__ __launch_bounds__(256) void k_linkpred(const int* __restrict__ sidx,
                                                  const int* __restrict__ didx,
                                                  const float* __restrict__ z,
                                                  const float* __restrict__ Wl,
                                                  const float* __restrict__ bl,
                                                  float* __restrict__ pred) {
    int t = blockIdx.x * blockDim.x + threadIdx.x;
    int lane = t & 63;
    int e = t >> 6;
    if (e >= NEL) return;                      // wave-uniform (e = t>>6)
    float wv = Wl[lane];
    int node = (lane < 32) ? sidx[e] : didx[e];
    float v = z[node * 32 + (lane & 31)] * wv;
#pragma unroll
    for (int off = 32; off > 0; off >>= 1) v += __shfl_down(v, off, 64);
    if (lane == 0) pred[e] = v + bl[0];
}

extern "C" void kernel_launch(void* const* d_in, const int* in_sizes, int n_in,
                              void* d_out, int out_size, void* d_ws, size_t ws_size,
                              hipStream_t stream) {
    const float* x    = (const float*)d_in[0];
    const float* pos  = (const float*)d_in[1];
    const float* W1   = (const float*)d_in[2];
    const float* b1   = (const float*)d_in[3];
    const float* W2   = (const float*)d_in[4];
    const float* b2   = (const float*)d_in[5];
    const float* Wl   = (const float*)d_in[6];
    const float* bl   = (const float*)d_in[7];
    const int*   ei   = (const int*)d_in[8];   // [2, NE]
    const int*   eli  = (const int*)d_in[9];   // [2, NEL]
    const int* src  = ei;
    const int* dst  = ei + NE;
    const int* lsrc = eli;
    const int* ldst = eli + NEL;

    float* out_z    = (float*)d_out;            // [NN, 32]
    float* out_pred = (float*)d_out + NN * 32;  // [NEL]

    // workspace: dinv[NN]f | off[NN]i | bsum[NB] | ebsum[NB] | esrc[NE]int2 |
    //            hw1[NN*64]h | h2[NN*64]h | hw2[NN*32]h   = 45.6 MB total
    //            (equal to the R3-proven footprint)
    float*  dinv  = (float*)d_ws;
    int*    off   = (int*)(dinv + NN);
    int*    bsum  = off + NN;
    int*    ebsum = bsum + NB;
    int2*   esrc  = (int2*)(ebsum + NB);
    __half* hw1   = (__half*)(esrc + NE);
    __half* h2    = hw1 + NN * 64;
    __half* hw2   = h2 + NN * 64;

    // 1) CSR build + dinv (hist/fill XCD-partitioned: grid = 8 groups x 256)
    k_zero<<<(NN + 255) / 256, 256, 0, stream>>>(off);
    k_hist<<<2048, 256, 0, stream>>>(dst, off);
    k_dinv<<<(NN + 255) / 256, 256, 0, stream>>>(off, dinv);
    k_bsum<<<NB, 256, 0, stream>>>(off, bsum);
    k_bscan<<<1, 512, 0, stream>>>(bsum, ebsum);
    k_offsets<<<NB, 256, 0, stream>>>(off, ebsum);
    k_fill<<<2048, 256, 0, stream>>>(src, dst, dinv, off, esrc);

    // 2) hw1 = [x|pos] @ W1 (fp16 out), tiled GEMM
    k_hw1<<<(NN + TM - 1) / TM, 256, 0, stream>>>(x, pos, W1, hw1);

    // 3) layer-1 gather + bias + relu -> h2 (fp16), shuffle-free
    k_gather1<<<NN / 4, 256, 0, stream>>>(off, esrc, dinv, hw1, b1, h2);

    // 4) hw2 = h2 @ W2 (fp16), tiled GEMM
    k_hw2<<<(NN + TM2 - 1) / TM2, 256, 0, stream>>>(h2, W2, hw2);

    // 5) layer-2 gather + bias -> z (fp32 out), shuffle-free edge loop
    k_gather2<<<NN / 4, 256, 0, stream>>>(off, esrc, dinv, hw2, b2, out_z);

    // 6) link prediction
    k_linkpred<<<(NEL * 64 + 255) / 256, 256, 0, stream>>>(lsrc, ldst, out_z, Wl, bl, out_pred);
}

// Round 10
// 438.616 us; speedup vs baseline: 1.0528x; 1.0528x over previous
//
#include <hip/hip_runtime.h>
#include <hip/hip_fp16.h>

#define NN 100000     // num nodes
#define NE 1600000    // num edges
#define NEL 200000    // link-pred edges
#define NB 391        // (NN+255)/256 scan blocks
#define TM 64         // nodes per block in k_hw1
#define TM2 128       // nodes per block in k_hw2
#define RNG (NN / 8)  // 12500 dst-nodes per XCD partition

// ---------------- CSR build ----------------
__global__ void k_zero(int* __restrict__ c) {
    int i = blockIdx.x * blockDim.x + threadIdx.x;
    if (i < NN) c[i] = 0;
}

// Partitioned histogram: group g = blockIdx&7 (XCD swizzle heuristic) counts
// only dst in [g*RNG,(g+1)*RNG) -> atomics stay in one XCD's L2 slice.
__global__ __launch_bounds__(256) void k_hist(const int* __restrict__ dst,
                                              int* __restrict__ c) {
    int g  = blockIdx.x & 7;
    int kg = blockIdx.x >> 3;
    int lo = g * RNG, hi = lo + RNG;
    int stride = (gridDim.x >> 3) * 256;
    for (int e = kg * 256 + threadIdx.x; e < NE; e += stride) {
        int d = dst[e];
        if (d >= lo && d < hi) atomicAdd(&c[d], 1);
    }
}

__global__ void k_dinv(const int* __restrict__ c, float* __restrict__ dinv) {
    int i = blockIdx.x * blockDim.x + threadIdx.x;
    if (i < NN) dinv[i] = rsqrtf((float)(c[i] + 1));   // +1 self-loop
}

__global__ void k_bsum(const int* __restrict__ c, int* __restrict__ bsum) {
    __shared__ int s[256];
    int t = threadIdx.x, i = blockIdx.x * 256 + t;
    s[t] = (i < NN) ? c[i] : 0;
    __syncthreads();
    for (int st = 128; st > 0; st >>= 1) {
        if (t < st) s[t] += s[t + st];
        __syncthreads();
    }
    if (t == 0) bsum[blockIdx.x] = s[0];
}

__global__ void k_bscan(const int* __restrict__ bsum, int* __restrict__ ebsum) {
    __shared__ int s[512];
    int t = threadIdx.x;
    int v = (t < NB) ? bsum[t] : 0;
    s[t] = v;
    __syncthreads();
    for (int st = 1; st < 512; st <<= 1) {
        int tmp = (t >= st) ? s[t - st] : 0;
        __syncthreads();
        s[t] += tmp;
        __syncthreads();
    }
    if (t < NB) ebsum[t] = s[t] - v;   // exclusive
}

__global__ void k_offsets(int* __restrict__ c, const int* __restrict__ ebsum) {
    __shared__ int s[256];
    int t = threadIdx.x, i = blockIdx.x * 256 + t;
    int v = (i < NN) ? c[i] : 0;
    s[t] = v;
    __syncthreads();
    for (int st = 1; st < 256; st <<= 1) {
        int tmp = (t >= st) ? s[t - st] : 0;
        __syncthreads();
        s[t] += tmp;
        __syncthreads();
    }
    if (i < NN) c[i] = ebsum[blockIdx.x] + s[t] - v;   // exclusive offsets (in place)
}

// Partitioned fill, 4B records (R8's 8B {src,dinv} records doubled the
// scattered-write traffic; pre-scaled features make dinv[s] unnecessary).
__global__ __launch_bounds__(256) void k_fill(const int* __restrict__ src,
                                              const int* __restrict__ dst,
                                              int* __restrict__ off,
                                              int* __restrict__ csr) {
    int g  = blockIdx.x & 7;
    int kg = blockIdx.x >> 3;
    int lo = g * RNG, hi = lo + RNG;
    int stride = (gridDim.x >> 3) * 256;
    for (int e = kg * 256 + threadIdx.x; e < NE; e += stride) {
        int d = dst[e];
        if (d >= lo && d < hi) {
            int p = atomicAdd(&off[d], 1);
            csr[p] = src[e];
        }
    }
    // post-fill: off[d] == end of row d; row d = [off[d-1], off[d]), off[-1]=0
}

// ---------------- hw1' = dinv * ([x|pos] @ W1)  (80 -> 64), fp16 out -------
// Pre-scaled by dinv[node]: the gathers then need only "acc += hw1'[s]".
__global__ __launch_bounds__(256) void k_hw1(const float* __restrict__ x,
                                             const float* __restrict__ pos,
                                             const float* __restrict__ W1,
                                             const float* __restrict__ dinv,
                                             __half* __restrict__ hw1) {
    __shared__ float sh[TM * 80];   // [node][feat 0..79]
    __shared__ float sw[80 * 64];   // [k][j]
    int tid = threadIdx.x;
    for (int t = tid; t < 80 * 64; t += 256) sw[t] = W1[t];
    int nb = blockIdx.x * TM;
    for (int i = tid; i < TM * 64; i += 256) {       // x part (coalesced)
        int node = i >> 6, ch = i & 63;
        int g = nb + node;
        sh[node * 80 + ch] = (g < NN) ? x[g * 64 + ch] : 0.0f;
    }
    for (int i = tid; i < TM * 16; i += 256) {       // pos part (coalesced)
        int node = i >> 4, ch = i & 15;
        int g = nb + node;
        sh[node * 80 + 64 + ch] = (g < NN) ? pos[g * 16 + ch] : 0.0f;
    }
    __syncthreads();
    int j  = (tid & 15) * 4;        // output channel base
    int nl = (tid >> 4) * 4;        // local node base
    float a00=0,a01=0,a02=0,a03=0, a10=0,a11=0,a12=0,a13=0;
    float a20=0,a21=0,a22=0,a23=0, a30=0,a31=0,a32=0,a33=0;
#pragma unroll 4
    for (int k = 0; k < 80; ++k) {
        float4 wv = *(const float4*)&sw[k * 64 + j];
        float h0 = sh[(nl + 0) * 80 + k];
        float h1 = sh[(nl + 1) * 80 + k];
        float h2 = sh[(nl + 2) * 80 + k];
        float h3 = sh[(nl + 3) * 80 + k];
        a00 += h0 * wv.x; a01 += h0 * wv.y; a02 += h0 * wv.z; a03 += h0 * wv.w;
        a10 += h1 * wv.x; a11 += h1 * wv.y; a12 += h1 * wv.z; a13 += h1 * wv.w;
        a20 += h2 * wv.x; a21 += h2 * wv.y; a22 += h2 * wv.z; a23 += h2 * wv.w;
        a30 += h3 * wv.x; a31 += h3 * wv.y; a32 += h3 * wv.z; a33 += h3 * wv.w;
    }
    int g0 = nb + nl;
    union { __half2 h2v[2]; float2 f2; } u;
#define STORE_ROW(r, b0, b1, b2, b3)                                          \
    if (g0 + r < NN) {                                                        \
        float sc = dinv[g0 + r];                                              \
        u.h2v[0] = __floats2half2_rn(b0 * sc, b1 * sc);                       \
        u.h2v[1] = __floats2half2_rn(b2 * sc, b3 * sc);                       \
        *(float2*)&hw1[(g0 + r) * 64 + j] = u.f2;                             \
    }
    STORE_ROW(0, a00, a01, a02, a03)
    STORE_ROW(1, a10, a11, a12, a13)
    STORE_ROW(2, a20, a21, a22, a23)
    STORE_ROW(3, a30, a31, a32, a33)
#undef STORE_ROW
}

// ---------------- layer-1 gather (pre-scaled, shuffle-free, 8-deep MLP) ----
// h2[d][c] = relu(b1[c] + dinv[d] * (sum_e hw1'[s] + hw1'[d]))
//   where hw1' = hw1 * dinv[node]  (so hw1'[d]*dd == hw1[d]*dd^2).
// Per edge: one wave-uniform 4B load (scalar-pipe candidate via
// readfirstlane'd bounds) + one coalesced 128B gather + one add.
__global__ __launch_bounds__(256) void k_gather1(const int* __restrict__ off,
                                                 const int* __restrict__ csr,
                                                 const float* __restrict__ dinv,
                                                 const __half* __restrict__ hw,
                                                 const float* __restrict__ b1,
                                                 __half* __restrict__ h2out) {
    int lane = threadIdx.x & 63;
    int wave = threadIdx.x >> 6;
    int d = blockIdx.x * 4 + wave;             // grid = NN/4 exactly
    int start = (d == 0) ? 0 : off[d - 1];
    int end = off[d];
    start = __builtin_amdgcn_readfirstlane(start);   // force SGPR bounds ->
    end   = __builtin_amdgcn_readfirstlane(end);     // scalar csr loads
    float dd = dinv[d];
    float hself = __half2float(hw[d * 64 + lane]);   // hoisted: overlaps loop
    float acc0 = 0.0f, acc1 = 0.0f, acc2 = 0.0f, acc3 = 0.0f;
    int e = start;
    for (; e + 7 < end; e += 8) {              // 8 outstanding gathers
        int s0 = csr[e],     s1 = csr[e + 1];
        int s2 = csr[e + 2], s3 = csr[e + 3];
        int s4 = csr[e + 4], s5 = csr[e + 5];
        int s6 = csr[e + 6], s7 = csr[e + 7];
        float g0 = __half2float(hw[s0 * 64 + lane]);
        float g1 = __half2float(hw[s1 * 64 + lane]);
        float g2 = __half2float(hw[s2 * 64 + lane]);
        float g3 = __half2float(hw[s3 * 64 + lane]);
        float g4 = __half2float(hw[s4 * 64 + lane]);
        float g5 = __half2float(hw[s5 * 64 + lane]);
        float g6 = __half2float(hw[s6 * 64 + lane]);
        float g7 = __half2float(hw[s7 * 64 + lane]);
        acc0 += g0; acc1 += g1; acc2 += g2; acc3 += g3;
        acc0 += g4; acc1 += g5; acc2 += g6; acc3 += g7;
    }
    for (; e < end; ++e)                       // uniform remainder
        acc0 += __half2float(hw[csr[e] * 64 + lane]);
    float v = fmaxf(b1[lane] + dd * (((acc0 + acc1) + (acc2 + acc3)) + hself), 0.0f);
    h2out[d * 64 + lane] = __float2half_rn(v);
}

// ---------------- hw2' = dinv * (h2 @ W2)  (64 -> 32), fp16 in/out ---------
__global__ __launch_bounds__(256) void k_hw2(const __half* __restrict__ h2,
                                             const float* __restrict__ W2,
                                             const float* __restrict__ dinv,
                                             __half* __restrict__ hw2) {
    __shared__ float sh[TM2 * 65];  // [node][feat], stride 65 (pad)
    __shared__ float sw[64 * 32];   // [k][j]
    int tid = threadIdx.x;
    for (int t = tid; t < 64 * 32; t += 256) sw[t] = W2[t];
    int nb = blockIdx.x * TM2;
    for (int i = tid; i < TM2 * 64; i += 256) {      // coalesced 2B loads
        int node = i >> 6, ch = i & 63;
        int g = nb + node;
        sh[node * 65 + ch] = (g < NN) ? __half2float(h2[g * 64 + ch]) : 0.0f;
    }
    __syncthreads();
    int j  = (tid & 7) * 4;         // output channel base (32 ch -> 8 groups)
    int nl = (tid >> 3) * 4;        // local node base (128 nodes -> 32 groups)
    float a00=0,a01=0,a02=0,a03=0, a10=0,a11=0,a12=0,a13=0;
    float a20=0,a21=0,a22=0,a23=0, a30=0,a31=0,a32=0,a33=0;
#pragma unroll 4
    for (int k = 0; k < 64; ++k) {
        float4 wv = *(const float4*)&sw[k * 32 + j];
        float h0 = sh[(nl + 0) * 65 + k];
        float h1 = sh[(nl + 1) * 65 + k];
        float h2v = sh[(nl + 2) * 65 + k];
        float h3 = sh[(nl + 3) * 65 + k];
        a00 += h0 * wv.x;  a01 += h0 * wv.y;  a02 += h0 * wv.z;  a03 += h0 * wv.w;
        a10 += h1 * wv.x;  a11 += h1 * wv.y;  a12 += h1 * wv.z;  a13 += h1 * wv.w;
        a20 += h2v * wv.x; a21 += h2v * wv.y; a22 += h2v * wv.z; a23 += h2v * wv.w;
        a30 += h3 * wv.x;  a31 += h3 * wv.y;  a32 += h3 * wv.z;  a33 += h3 * wv.w;
    }
    int g0 = nb + nl;
    union { __half2 h2v2[2]; float2 f2; } u;
#define STORE_ROW(r, b0, b1, b2, b3)                                          \
    if (g0 + r < NN) {                                                        \
        float sc = dinv[g0 + r];                                              \
        u.h2v2[0] = __floats2half2_rn(b0 * sc, b1 * sc);                      \
        u.h2v2[1] = __floats2half2_rn(b2 * sc, b3 * sc);                      \
        *(float2*)&hw2[(g0 + r) * 32 + j] = u.f2;                             \
    }
    STORE_ROW(0, a00, a01, a02, a03)
    STORE_ROW(1, a10, a11, a12, a13)
    STORE_ROW(2, a20, a21, a22, a23)
    STORE_ROW(3, a30, a31, a32, a33)
#undef STORE_ROW
}

// ---------------- layer-2 gather (C=32, pre-scaled, 8 outstanding) ---------
// z[d][j] = b2[j] + dinv[d] * (sum_e hw2'[s] + hw2'[d])
// Half h takes edges start+h, start+h+2, ...; 4 accs/half = 8 outstanding
// per wave. Divergent tail is safe (no cross-lane ops inside); the single
// half-combine __shfl runs at full reconvergence.
__global__ __launch_bounds__(256) void k_gather2(const int* __restrict__ off,
                                                 const int* __restrict__ csr,
                                                 const float* __restrict__ dinv,
                                                 const __half* __restrict__ hw,
                                                 const float* __restrict__ b2,
                                                 float* __restrict__ outz) {
    int lane = threadIdx.x & 63;
    int half = lane >> 5;
    int j = lane & 31;
    int wave = threadIdx.x >> 6;
    int d = blockIdx.x * 4 + wave;             // grid = NN/4 exactly
    int start = (d == 0) ? 0 : off[d - 1];
    int end = off[d];
    start = __builtin_amdgcn_readfirstlane(start);
    end   = __builtin_amdgcn_readfirstlane(end);
    float dd = dinv[d];
    float hself = __half2float(hw[d * 32 + j]);      // hoisted
    float accA = 0.0f, accB = 0.0f, accC = 0.0f, accD = 0.0f;
    int e = start;
    for (; e + 7 < end; e += 8) {              // 4 gathers per half in flight
        int sA = csr[e + half];
        int sB = csr[e + half + 2];
        int sC = csr[e + half + 4];
        int sD = csr[e + half + 6];
        accA += __half2float(hw[sA * 32 + j]);
        accB += __half2float(hw[sB * 32 + j]);
        accC += __half2float(hw[sC * 32 + j]);
        accD += __half2float(hw[sD * 32 + j]);
    }
    for (int ee = e + half; ee < end; ee += 2)       // divergent-safe tail
        accA += __half2float(hw[csr[ee] * 32 + j]);
    float acc = (accA + accB) + (accC + accD);
    acc += __shfl(acc, lane ^ 32, 64);         // combine halves (full exec)
    if (half == 0)
        outz[d * 32 + j] = b2[j] + dd * (acc + hself);
}

// ---------------- link prediction head ----------------
__global__ __launch_bounds__(256) void k_linkpred(const int* __restrict__ sidx,
                                                  const int* __restrict__ didx,
                                                  const float* __restrict__ z,
                                                  const float* __restrict__ Wl,
                                                  const float* __restrict__ bl,
                                                  float* __restrict__ pred) {
    int t = blockIdx.x * blockDim.x + threadIdx.x;
    int lane = t & 63;
    int e = t >> 6;
    if (e >= NEL) return;                      // wave-uniform (e = t>>6)
    float wv = Wl[lane];
    int node = (lane < 32) ? sidx[e] : didx[e];
    float v = z[node * 32 + (lane & 31)] * wv;
#pragma unroll
    for (int off = 32; off > 0; off >>= 1) v += __shfl_down(v, off, 64);
    if (lane == 0) pred[e] = v + bl[0];
}

extern "C" void kernel_launch(void* const* d_in, const int* in_sizes, int n_in,
                              void* d_out, int out_size, void* d_ws, size_t ws_size,
                              hipStream_t stream) {
    const float* x    = (const float*)d_in[0];
    const float* pos  = (const float*)d_in[1];
    const float* W1   = (const float*)d_in[2];
    const float* b1   = (const float*)d_in[3];
    const float* W2   = (const float*)d_in[4];
    const float* b2   = (const float*)d_in[5];
    const float* Wl   = (const float*)d_in[6];
    const float* bl   = (const float*)d_in[7];
    const int*   ei   = (const int*)d_in[8];   // [2, NE]
    const int*   eli  = (const int*)d_in[9];   // [2, NEL]
    const int* src  = ei;
    const int* dst  = ei + NE;
    const int* lsrc = eli;
    const int* ldst = eli + NEL;

    float* out_z    = (float*)d_out;            // [NN, 32]
    float* out_pred = (float*)d_out + NN * 32;  // [NEL]

    // workspace: dinv[NN]f | off[NN]i | bsum[NB] | ebsum[NB] | csr[NE]i |
    //            hw1'[NN*64]h | h2[NN*64]h | hw2'[NN*32]h   ~= 39.2 MB
    float*  dinv  = (float*)d_ws;
    int*    off   = (int*)(dinv + NN);
    int*    bsum  = off + NN;
    int*    ebsum = bsum + NB;
    int*    csr   = ebsum + NB;
    __half* hw1   = (__half*)(csr + NE);
    __half* h2    = hw1 + NN * 64;
    __half* hw2   = h2 + NN * 64;

    // 1) CSR build + dinv (hist/fill XCD-partitioned: grid = 8 groups x 256)
    k_zero<<<(NN + 255) / 256, 256, 0, stream>>>(off);
    k_hist<<<2048, 256, 0, stream>>>(dst, off);
    k_dinv<<<(NN + 255) / 256, 256, 0, stream>>>(off, dinv);
    k_bsum<<<NB, 256, 0, stream>>>(off, bsum);
    k_bscan<<<1, 512, 0, stream>>>(bsum, ebsum);
    k_offsets<<<NB, 256, 0, stream>>>(off, ebsum);
    k_fill<<<2048, 256, 0, stream>>>(src, dst, off, csr);

    // 2) hw1' = dinv * ([x|pos] @ W1), fp16
    k_hw1<<<(NN + TM - 1) / TM, 256, 0, stream>>>(x, pos, W1, dinv, hw1);

    // 3) layer-1 gather + bias + relu -> h2 (fp16), shuffle-free, 8-deep
    k_gather1<<<NN / 4, 256, 0, stream>>>(off, csr, dinv, hw1, b1, h2);

    // 4) hw2' = dinv * (h2 @ W2), fp16
    k_hw2<<<(NN + TM2 - 1) / TM2, 256, 0, stream>>>(h2, W2, dinv, hw2);

    // 5) layer-2 gather + bias -> z (fp32 out)
    k_gather2<<<NN / 4, 256, 0, stream>>>(off, csr, dinv, hw2, b2, out_z);

    // 6) link prediction
    k_linkpred<<<(NEL * 64 + 255) / 256, 256, 0, stream>>>(lsrc, ldst, out_z, Wl, bl, out_pred);
}

// Round 11
// 420.587 us; speedup vs baseline: 1.0979x; 1.0429x over previous
//
#include <hip/hip_runtime.h>
#include <hip/hip_fp16.h>

#define NN 100000     // num nodes
#define NE 1600000    // num edges
#define NEL 200000    // link-pred edges
#define NB 391        // (NN+255)/256 scan blocks
#define TM 64         // nodes per block in k_hw1
#define TM2 128       // nodes per block in k_hw2
#define RNG (NN / 8)  // 12500 dst-nodes per XCD partition

// ---------------- CSR build ----------------
__global__ void k_zero(int* __restrict__ c) {
    int i = blockIdx.x * blockDim.x + threadIdx.x;
    if (i < NN) c[i] = 0;
}

// Partitioned histogram: group g = blockIdx&7 (XCD swizzle heuristic) counts
// only dst in [g*RNG,(g+1)*RNG). Scan loads are NON-TEMPORAL so the 6.4 MB
// read stream doesn't evict the hot 50 KB cursor slice from L2 (R9
// post-mortem: stream-driven eviction, not placement, was the amplifier).
__global__ __launch_bounds__(256) void k_hist(const int* __restrict__ dst,
                                              int* __restrict__ c) {
    int g  = blockIdx.x & 7;
    int kg = blockIdx.x >> 3;
    int lo = g * RNG, hi = lo + RNG;
    int stride = (gridDim.x >> 3) * 256;
    for (int e = kg * 256 + threadIdx.x; e < NE; e += stride) {
        int d = __builtin_nontemporal_load(dst + e);
        if (d >= lo && d < hi) atomicAdd(&c[d], 1);
    }
}

__global__ void k_bsum(const int* __restrict__ c, int* __restrict__ bsum) {
    __shared__ int s[256];
    int t = threadIdx.x, i = blockIdx.x * 256 + t;
    s[t] = (i < NN) ? c[i] : 0;
    __syncthreads();
    for (int st = 128; st > 0; st >>= 1) {
        if (t < st) s[t] += s[t + st];
        __syncthreads();
    }
    if (t == 0) bsum[blockIdx.x] = s[0];
}

__global__ void k_bscan(const int* __restrict__ bsum, int* __restrict__ ebsum) {
    __shared__ int s[512];
    int t = threadIdx.x;
    int v = (t < NB) ? bsum[t] : 0;
    s[t] = v;
    __syncthreads();
    for (int st = 1; st < 512; st <<= 1) {
        int tmp = (t >= st) ? s[t - st] : 0;
        __syncthreads();
        s[t] += tmp;
        __syncthreads();
    }
    if (t < NB) ebsum[t] = s[t] - v;   // exclusive
}

// Exclusive offsets in place; also emits dinv = rsqrt(count+1) (folded from
// the old k_dinv launch — reads the count anyway).
__global__ void k_offsets(int* __restrict__ c, const int* __restrict__ ebsum,
                          float* __restrict__ dinv) {
    __shared__ int s[256];
    int t = threadIdx.x, i = blockIdx.x * 256 + t;
    int v = (i < NN) ? c[i] : 0;
    s[t] = v;
    __syncthreads();
    for (int st = 1; st < 256; st <<= 1) {
        int tmp = (t >= st) ? s[t - st] : 0;
        __syncthreads();
        s[t] += tmp;
        __syncthreads();
    }
    if (i < NN) {
        dinv[i] = rsqrtf((float)(v + 1));               // +1 self-loop
        c[i] = ebsum[blockIdx.x] + s[t] - v;            // exclusive offset
    }
}

// Partitioned fill, 4B records, NON-TEMPORAL scan loads: the dst+src stream
// (12.8 MB/group) no longer washes the 850 KB csr+cursor slice out of L2,
// so 64B lines accumulate all 16 entries before one eviction (R9 measured
// 73 MB WRITE for 6.4 MB of payload without this).
__global__ __launch_bounds__(256) void k_fill(const int* __restrict__ src,
                                              const int* __restrict__ dst,
                                              int* __restrict__ off,
                                              int* __restrict__ csr) {
    int g  = blockIdx.x & 7;
    int kg = blockIdx.x >> 3;
    int lo = g * RNG, hi = lo + RNG;
    int stride = (gridDim.x >> 3) * 256;
    for (int e = kg * 256 + threadIdx.x; e < NE; e += stride) {
        int d = __builtin_nontemporal_load(dst + e);
        if (d >= lo && d < hi) {
            int s = __builtin_nontemporal_load(src + e);
            int p = atomicAdd(&off[d], 1);
            csr[p] = s;
        }
    }
    // post-fill: off[d] == end of row d; row d = [off[d-1], off[d]), off[-1]=0
}

// ---------------- hw1' = dinv * ([x|pos] @ W1)  (80 -> 64), fp16 out -------
// Pre-scaled by dinv[node]: the gathers then need only "acc += hw1'[s]".
__global__ __launch_bounds__(256) void k_hw1(const float* __restrict__ x,
                                             const float* __restrict__ pos,
                                             const float* __restrict__ W1,
                                             const float* __restrict__ dinv,
                                             __half* __restrict__ hw1) {
    __shared__ float sh[TM * 80];   // [node][feat 0..79]
    __shared__ float sw[80 * 64];   // [k][j]
    int tid = threadIdx.x;
    for (int t = tid; t < 80 * 64; t += 256) sw[t] = W1[t];
    int nb = blockIdx.x * TM;
    for (int i = tid; i < TM * 64; i += 256) {       // x part (coalesced)
        int node = i >> 6, ch = i & 63;
        int g = nb + node;
        sh[node * 80 + ch] = (g < NN) ? x[g * 64 + ch] : 0.0f;
    }
    for (int i = tid; i < TM * 16; i += 256) {       // pos part (coalesced)
        int node = i >> 4, ch = i & 15;
        int g = nb + node;
        sh[node * 80 + 64 + ch] = (g < NN) ? pos[g * 16 + ch] : 0.0f;
    }
    __syncthreads();
    int j  = (tid & 15) * 4;        // output channel base
    int nl = (tid >> 4) * 4;        // local node base
    float a00=0,a01=0,a02=0,a03=0, a10=0,a11=0,a12=0,a13=0;
    float a20=0,a21=0,a22=0,a23=0, a30=0,a31=0,a32=0,a33=0;
#pragma unroll 4
    for (int k = 0; k < 80; ++k) {
        float4 wv = *(const float4*)&sw[k * 64 + j];
        float h0 = sh[(nl + 0) * 80 + k];
        float h1 = sh[(nl + 1) * 80 + k];
        float h2 = sh[(nl + 2) * 80 + k];
        float h3 = sh[(nl + 3) * 80 + k];
        a00 += h0 * wv.x; a01 += h0 * wv.y; a02 += h0 * wv.z; a03 += h0 * wv.w;
        a10 += h1 * wv.x; a11 += h1 * wv.y; a12 += h1 * wv.z; a13 += h1 * wv.w;
        a20 += h2 * wv.x; a21 += h2 * wv.y; a22 += h2 * wv.z; a23 += h2 * wv.w;
        a30 += h3 * wv.x; a31 += h3 * wv.y; a32 += h3 * wv.z; a33 += h3 * wv.w;
    }
    int g0 = nb + nl;
    union { __half2 h2v[2]; float2 f2; } u;
#define STORE_ROW(r, b0, b1, b2, b3)                                          \
    if (g0 + r < NN) {                                                        \
        float sc = dinv[g0 + r];                                              \
        u.h2v[0] = __floats2half2_rn(b0 * sc, b1 * sc);                       \
        u.h2v[1] = __floats2half2_rn(b2 * sc, b3 * sc);                       \
        *(float2*)&hw1[(g0 + r) * 64 + j] = u.f2;                             \
    }
    STORE_ROW(0, a00, a01, a02, a03)
    STORE_ROW(1, a10, a11, a12, a13)
    STORE_ROW(2, a20, a21, a22, a23)
    STORE_ROW(3, a30, a31, a32, a33)
#undef STORE_ROW
}

// ---------------- layer-1 gather (pre-scaled, shuffle-free, 8-deep MLP) ----
// h2[d][c] = relu(b1[c] + dinv[d] * (sum_e hw1'[s] + hw1'[d]))
__global__ __launch_bounds__(256) void k_gather1(const int* __restrict__ off,
                                                 const int* __restrict__ csr,
                                                 const float* __restrict__ dinv,
                                                 const __half* __restrict__ hw,
                                                 const float* __restrict__ b1,
                                                 __half* __restrict__ h2out) {
    int lane = threadIdx.x & 63;
    int wave = threadIdx.x >> 6;
    int d = blockIdx.x * 4 + wave;             // grid = NN/4 exactly
    int start = (d == 0) ? 0 : off[d - 1];
    int end = off[d];
    start = __builtin_amdgcn_readfirstlane(start);   // force SGPR bounds ->
    end   = __builtin_amdgcn_readfirstlane(end);     // scalar csr loads
    float dd = dinv[d];
    float hself = __half2float(hw[d * 64 + lane]);   // hoisted: overlaps loop
    float acc0 = 0.0f, acc1 = 0.0f, acc2 = 0.0f, acc3 = 0.0f;
    int e = start;
    for (; e + 7 < end; e += 8) {              // 8 outstanding gathers
        int s0 = csr[e],     s1 = csr[e + 1];
        int s2 = csr[e + 2], s3 = csr[e + 3];
        int s4 = csr[e + 4], s5 = csr[e + 5];
        int s6 = csr[e + 6], s7 = csr[e + 7];
        float g0 = __half2float(hw[s0 * 64 + lane]);
        float g1 = __half2float(hw[s1 * 64 + lane]);
        float g2 = __half2float(hw[s2 * 64 + lane]);
        float g3 = __half2float(hw[s3 * 64 + lane]);
        float g4 = __half2float(hw[s4 * 64 + lane]);
        float g5 = __half2float(hw[s5 * 64 + lane]);
        float g6 = __half2float(hw[s6 * 64 + lane]);
        float g7 = __half2float(hw[s7 * 64 + lane]);
        acc0 += g0; acc1 += g1; acc2 += g2; acc3 += g3;
        acc0 += g4; acc1 += g5; acc2 += g6; acc3 += g7;
    }
    for (; e < end; ++e)                       // uniform remainder
        acc0 += __half2float(hw[csr[e] * 64 + lane]);
    float v = fmaxf(b1[lane] + dd * (((acc0 + acc1) + (acc2 + acc3)) + hself), 0.0f);
    h2out[d * 64 + lane] = __float2half_rn(v);
}

// ---------------- hw2' = dinv * (h2 @ W2)  (64 -> 32), fp16 in/out ---------
__global__ __launch_bounds__(256) void k_hw2(const __half* __restrict__ h2,
                                             const float* __restrict__ W2,
                                             const float* __restrict__ dinv,
                                             __half* __restrict__ hw2) {
    __shared__ float sh[TM2 * 65];  // [node][feat], stride 65 (pad)
    __shared__ float sw[64 * 32];   // [k][j]
    int tid = threadIdx.x;
    for (int t = tid; t < 64 * 32; t += 256) sw[t] = W2[t];
    int nb = blockIdx.x * TM2;
    for (int i = tid; i < TM2 * 64; i += 256) {      // coalesced 2B loads
        int node = i >> 6, ch = i & 63;
        int g = nb + node;
        sh[node * 65 + ch] = (g < NN) ? __half2float(h2[g * 64 + ch]) : 0.0f;
    }
    __syncthreads();
    int j  = (tid & 7) * 4;         // output channel base (32 ch -> 8 groups)
    int nl = (tid >> 3) * 4;        // local node base (128 nodes -> 32 groups)
    float a00=0,a01=0,a02=0,a03=0, a10=0,a11=0,a12=0,a13=0;
    float a20=0,a21=0,a22=0,a23=0, a30=0,a31=0,a32=0,a33=0;
#pragma unroll 4
    for (int k = 0; k < 64; ++k) {
        float4 wv = *(const float4*)&sw[k * 32 + j];
        float h0 = sh[(nl + 0) * 65 + k];
        float h1 = sh[(nl + 1) * 65 + k];
        float h2v = sh[(nl + 2) * 65 + k];
        float h3 = sh[(nl + 3) * 65 + k];
        a00 += h0 * wv.x;  a01 += h0 * wv.y;  a02 += h0 * wv.z;  a03 += h0 * wv.w;
        a10 += h1 * wv.x;  a11 += h1 * wv.y;  a12 += h1 * wv.z;  a13 += h1 * wv.w;
        a20 += h2v * wv.x; a21 += h2v * wv.y; a22 += h2v * wv.z; a23 += h2v * wv.w;
        a30 += h3 * wv.x;  a31 += h3 * wv.y;  a32 += h3 * wv.z;  a33 += h3 * wv.w;
    }
    int g0 = nb + nl;
    union { __half2 h2v2[2]; float2 f2; } u;
#define STORE_ROW(r, b0, b1, b2, b3)                                          \
    if (g0 + r < NN) {                                                        \
        float sc = dinv[g0 + r];                                              \
        u.h2v2[0] = __floats2half2_rn(b0 * sc, b1 * sc);                      \
        u.h2v2[1] = __floats2half2_rn(b2 * sc, b3 * sc);                      \
        *(float2*)&hw2[(g0 + r) * 32 + j] = u.f2;                             \
    }
    STORE_ROW(0, a00, a01, a02, a03)
    STORE_ROW(1, a10, a11, a12, a13)
    STORE_ROW(2, a20, a21, a22, a23)
    STORE_ROW(3, a30, a31, a32, a33)
#undef STORE_ROW
}

// ---------------- layer-2 gather (C=32, pre-scaled, 8 outstanding) ---------
// z[d][j] = b2[j] + dinv[d] * (sum_e hw2'[s] + hw2'[d])
__global__ __launch_bounds__(256) void k_gather2(const int* __restrict__ off,
                                                 const int* __restrict__ csr,
                                                 const float* __restrict__ dinv,
                                                 const __half* __restrict__ hw,
                                                 const float* __restrict__ b2,
                                                 float* __restrict__ outz) {
    int lane = threadIdx.x & 63;
    int half = lane >> 5;
    int j = lane & 31;
    int wave = threadIdx.x >> 6;
    int d = blockIdx.x * 4 + wave;             // grid = NN/4 exactly
    int start = (d == 0) ? 0 : off[d - 1];
    int end = off[d];
    start = __builtin_amdgcn_readfirstlane(start);
    end   = __builtin_amdgcn_readfirstlane(end);
    float dd = dinv[d];
    float hself = __half2float(hw[d * 32 + j]);      // hoisted
    float accA = 0.0f, accB = 0.0f, accC = 0.0f, accD = 0.0f;
    int e = start;
    for (; e + 7 < end; e += 8) {              // 4 gathers per half in flight
        int sA = csr[e + half];
        int sB = csr[e + half + 2];
        int sC = csr[e + half + 4];
        int sD = csr[e + half + 6];
        accA += __half2float(hw[sA * 32 + j]);
        accB += __half2float(hw[sB * 32 + j]);
        accC += __half2float(hw[sC * 32 + j]);
        accD += __half2float(hw[sD * 32 + j]);
    }
    for (int ee = e + half; ee < end; ee += 2)       // divergent-safe tail
        accA += __half2float(hw[csr[ee] * 32 + j]);
    float acc = (accA + accB) + (accC + accD);
    acc += __shfl(acc, lane ^ 32, 64);         // combine halves (full exec)
    if (half == 0)
        outz[d * 32 + j] = b2[j] + dd * (acc + hself);
}

// ---------------- link prediction head: 16 lanes per edge ------------------
// pred[e] = dot(z[s], Wl[0:32]) + dot(z[d], Wl[32:64]) + bl.
// 4 edges/wave, each lane holds float2 of each row -> 8 row-gathers in
// flight per wave (old version: 1 edge/wave, 200K serial reductions).
// Grid exact: NEL*16/256 = 12500 blocks -> full exec for the xor shuffles.
__global__ __launch_bounds__(256) void k_linkpred(const int* __restrict__ sidx,
                                                  const int* __restrict__ didx,
                                                  const float* __restrict__ z,
                                                  const float* __restrict__ Wl,
                                                  const float* __restrict__ bl,
                                                  float* __restrict__ pred) {
    int t = blockIdx.x * blockDim.x + threadIdx.x;
    int e = t >> 4;                            // edge per 16-lane group
    int l = t & 15;
    int s = sidx[e], d = didx[e];              // broadcast within group
    float2 zs = *(const float2*)&z[s * 32 + 2 * l];   // 128B coalesced/row
    float2 zd = *(const float2*)&z[d * 32 + 2 * l];
    float2 ws = *(const float2*)&Wl[2 * l];
    float2 wd = *(const float2*)&Wl[32 + 2 * l];
    float v = zs.x * ws.x + zs.y * ws.y + zd.x * wd.x + zd.y * wd.y;
    v += __shfl_xor(v, 1, 64);                 // reduce within 16-lane group
    v += __shfl_xor(v, 2, 64);
    v += __shfl_xor(v, 4, 64);
    v += __shfl_xor(v, 8, 64);
    if (l == 0) pred[e] = v + bl[0];
}

extern "C" void kernel_launch(void* const* d_in, const int* in_sizes, int n_in,
                              void* d_out, int out_size, void* d_ws, size_t ws_size,
                              hipStream_t stream) {
    const float* x    = (const float*)d_in[0];
    const float* pos  = (const float*)d_in[1];
    const float* W1   = (const float*)d_in[2];
    const float* b1   = (const float*)d_in[3];
    const float* W2   = (const float*)d_in[4];
    const float* b2   = (const float*)d_in[5];
    const float* Wl   = (const float*)d_in[6];
    const float* bl   = (const float*)d_in[7];
    const int*   ei   = (const int*)d_in[8];   // [2, NE]
    const int*   eli  = (const int*)d_in[9];   // [2, NEL]
    const int* src  = ei;
    const int* dst  = ei + NE;
    const int* lsrc = eli;
    const int* ldst = eli + NEL;

    float* out_z    = (float*)d_out;            // [NN, 32]
    float* out_pred = (float*)d_out + NN * 32;  // [NEL]

    // workspace: dinv[NN]f | off[NN]i | bsum[NB] | ebsum[NB] | csr[NE]i |
    //            hw1'[NN*64]h | h2[NN*64]h | hw2'[NN*32]h   ~= 39.2 MB
    float*  dinv  = (float*)d_ws;
    int*    off   = (int*)(dinv + NN);
    int*    bsum  = off + NN;
    int*    ebsum = bsum + NB;
    int*    csr   = ebsum + NB;
    __half* hw1   = (__half*)(csr + NE);
    __half* h2    = hw1 + NN * 64;
    __half* hw2   = h2 + NN * 64;

    // 1) CSR build + dinv (hist/fill XCD-partitioned, nt scan loads)
    k_zero<<<(NN + 255) / 256, 256, 0, stream>>>(off);
    k_hist<<<2048, 256, 0, stream>>>(dst, off);
    k_bsum<<<NB, 256, 0, stream>>>(off, bsum);
    k_bscan<<<1, 512, 0, stream>>>(bsum, ebsum);
    k_offsets<<<NB, 256, 0, stream>>>(off, ebsum, dinv);   // + dinv fused
    k_fill<<<2048, 256, 0, stream>>>(src, dst, off, csr);

    // 2) hw1' = dinv * ([x|pos] @ W1), fp16
    k_hw1<<<(NN + TM - 1) / TM, 256, 0, stream>>>(x, pos, W1, dinv, hw1);

    // 3) layer-1 gather + bias + relu -> h2 (fp16), shuffle-free, 8-deep
    k_gather1<<<NN / 4, 256, 0, stream>>>(off, csr, dinv, hw1, b1, h2);

    // 4) hw2' = dinv * (h2 @ W2), fp16
    k_hw2<<<(NN + TM2 - 1) / TM2, 256, 0, stream>>>(h2, W2, dinv, hw2);

    // 5) layer-2 gather + bias -> z (fp32 out)
    k_gather2<<<NN / 4, 256, 0, stream>>>(off, csr, dinv, hw2, b2, out_z);

    // 6) link prediction (16 lanes/edge, grid exact)
    k_linkpred<<<NEL * 16 / 256, 256, 0, stream>>>(lsrc, ldst, out_z, Wl, bl, out_pred);
}

// Round 12
// 309.546 us; speedup vs baseline: 1.4918x; 1.3587x over previous
//
#include <hip/hip_runtime.h>
#include <hip/hip_fp16.h>

#define NN 100000     // num nodes
#define NE 1600000    // num edges
#define NEL 200000    // link-pred edges
#define TM 64         // nodes per block in k_hw1
#define TM2 128       // nodes per block in k_hw2

// Bucketed CSR build: bucket = dst >> 9 (512 dsts per bucket).
#define NBUCK 196     // ceil(NN/512)
#define CAPB  10240   // per-bucket region capacity (mean 8192, sigma ~90)
#define TPE   8192    // edges per k_part block

// ---------------- CSR build, pass 0: init bucket cursors -------------------
__global__ void k_initcur(int* __restrict__ gcur) {
    int i = threadIdx.x;
    if (i < NBUCK) gcur[i] = i * CAPB;
}

// ---------------- CSR build, pass A: partition edges into buckets ----------
// Each block: LDS histogram over its 8192-edge tile -> one global atomicAdd
// per (block,bucket) reserves contiguous space -> ranked writes. Per-bucket
// runs of ~42 contiguous entries fill cache lines within the tile's
// lifetime -> ~1.2x write amp (R4/R9/R11 scattered fill measured 10-16x).
// Record: bits[25:17] = dst&511, bits[16:0] = src (src < 2^17).
__global__ __launch_bounds__(256) void k_part(const int* __restrict__ src,
                                              const int* __restrict__ dst,
                                              int* __restrict__ gcur,
                                              int* __restrict__ part) {
    __shared__ int hist[NBUCK];
    __shared__ int base[NBUCK];
    __shared__ int rk[NBUCK];
    int tid = threadIdx.x;
    for (int i = tid; i < NBUCK; i += 256) { hist[i] = 0; rk[i] = 0; }
    __syncthreads();
    int e0 = blockIdx.x * TPE;
    int e1 = min(e0 + TPE, NE);
    for (int e = e0 + tid; e < e1; e += 256)
        atomicAdd(&hist[dst[e] >> 9], 1);
    __syncthreads();
    for (int i = tid; i < NBUCK; i += 256)
        base[i] = atomicAdd(&gcur[i], hist[i]);
    __syncthreads();
    for (int e = e0 + tid; e < e1; e += 256) {
        int d = dst[e];
        int s = src[e];
        int b = d >> 9;
        int r = atomicAdd(&rk[b], 1);
        part[base[b] + r] = ((d & 511) << 17) | s;
    }
}

// ---------------- CSR build, pass B0: bucket-base exclusive scan -----------
__global__ void k_bscan2(const int* __restrict__ gcur, int* __restrict__ bbase) {
    __shared__ int s[256];
    int t = threadIdx.x;
    int cnt = (t < NBUCK) ? (gcur[t] - t * CAPB) : 0;
    s[t] = cnt;
    __syncthreads();
    for (int st = 1; st < 256; st <<= 1) {
        int tmp = (t >= st) ? s[t - st] : 0;
        __syncthreads();
        s[t] += tmp;
        __syncthreads();
    }
    if (t < NBUCK) bbase[t] = s[t] - cnt;   // exclusive
}

// ---------------- CSR build, pass B: per-bucket LDS sort -------------------
// One block per bucket. Local 512-slot histogram -> scan -> off[] (end
// convention: row d = [off[d-1], off[d])) + dinv -> LDS scatter -> one
// fully-coalesced csr write of the whole bucket.
__global__ __launch_bounds__(256) void k_build(const int* __restrict__ gcur,
                                               const int* __restrict__ bbase,
                                               const int* __restrict__ part,
                                               int* __restrict__ csr,
                                               int* __restrict__ off,
                                               float* __restrict__ dinv) {
    __shared__ int hist[512];
    __shared__ int loff[512];
    __shared__ int ssum[256];
    __shared__ int csrbuf[CAPB];
    int b = blockIdx.x;
    int tid = threadIdx.x;
    int cnt = gcur[b] - b * CAPB;
    int pbase = b * CAPB;
    int obase = bbase[b];
    hist[tid] = 0; hist[tid + 256] = 0;
    __syncthreads();
    for (int i = tid; i < cnt; i += 256)
        atomicAdd(&hist[part[pbase + i] >> 17], 1);
    __syncthreads();
    // exclusive scan of hist[512]: pair-sum -> 256-wide Hillis-Steele -> expand
    int a0 = hist[2 * tid], a1 = hist[2 * tid + 1];
    int pairs = a0 + a1;
    ssum[tid] = pairs;
    __syncthreads();
    for (int st = 1; st < 256; st <<= 1) {
        int tmp = (tid >= st) ? ssum[tid - st] : 0;
        __syncthreads();
        ssum[tid] += tmp;
        __syncthreads();
    }
    int pexcl = ssum[tid] - pairs;
    loff[2 * tid] = pexcl;
    loff[2 * tid + 1] = pexcl + a0;
    __syncthreads();
    // off[] + dinv for this bucket's dst range
    for (int i = tid; i < 512; i += 256) {
        int d = b * 512 + i;
        if (d < NN) {
            int c = hist[i];
            off[d] = obase + loff[i] + c;            // end of row d
            dinv[d] = rsqrtf((float)(c + 1));        // +1 self-loop
        }
    }
    // reuse hist as rank counters
    hist[tid] = 0; hist[tid + 256] = 0;
    __syncthreads();
    for (int i = tid; i < cnt; i += 256) {
        int rec = part[pbase + i];
        int dl = rec >> 17;
        int r = atomicAdd(&hist[dl], 1);
        csrbuf[loff[dl] + r] = rec & 0x1FFFF;
    }
    __syncthreads();
    for (int i = tid; i < cnt; i += 256)             // coalesced flush
        csr[obase + i] = csrbuf[i];
}

// ---------------- hw1' = dinv * ([x|pos] @ W1)  (80 -> 64), fp16 out -------
__global__ __launch_bounds__(256) void k_hw1(const float* __restrict__ x,
                                             const float* __restrict__ pos,
                                             const float* __restrict__ W1,
                                             const float* __restrict__ dinv,
                                             __half* __restrict__ hw1) {
    __shared__ float sh[TM * 80];   // [node][feat 0..79]
    __shared__ float sw[80 * 64];   // [k][j]
    int tid = threadIdx.x;
    for (int t = tid; t < 80 * 64; t += 256) sw[t] = W1[t];
    int nb = blockIdx.x * TM;
    for (int i = tid; i < TM * 64; i += 256) {       // x part (coalesced)
        int node = i >> 6, ch = i & 63;
        int g = nb + node;
        sh[node * 80 + ch] = (g < NN) ? x[g * 64 + ch] : 0.0f;
    }
    for (int i = tid; i < TM * 16; i += 256) {       // pos part (coalesced)
        int node = i >> 4, ch = i & 15;
        int g = nb + node;
        sh[node * 80 + 64 + ch] = (g < NN) ? pos[g * 16 + ch] : 0.0f;
    }
    __syncthreads();
    int j  = (tid & 15) * 4;        // output channel base
    int nl = (tid >> 4) * 4;        // local node base
    float a00=0,a01=0,a02=0,a03=0, a10=0,a11=0,a12=0,a13=0;
    float a20=0,a21=0,a22=0,a23=0, a30=0,a31=0,a32=0,a33=0;
#pragma unroll 4
    for (int k = 0; k < 80; ++k) {
        float4 wv = *(const float4*)&sw[k * 64 + j];
        float h0 = sh[(nl + 0) * 80 + k];
        float h1 = sh[(nl + 1) * 80 + k];
        float h2 = sh[(nl + 2) * 80 + k];
        float h3 = sh[(nl + 3) * 80 + k];
        a00 += h0 * wv.x; a01 += h0 * wv.y; a02 += h0 * wv.z; a03 += h0 * wv.w;
        a10 += h1 * wv.x; a11 += h1 * wv.y; a12 += h1 * wv.z; a13 += h1 * wv.w;
        a20 += h2 * wv.x; a21 += h2 * wv.y; a22 += h2 * wv.z; a23 += h2 * wv.w;
        a30 += h3 * wv.x; a31 += h3 * wv.y; a32 += h3 * wv.z; a33 += h3 * wv.w;
    }
    int g0 = nb + nl;
    union { __half2 h2v[2]; float2 f2; } u;
#define STORE_ROW(r, b0, b1, b2, b3)                                          \
    if (g0 + r < NN) {                                                        \
        float sc = dinv[g0 + r];                                              \
        u.h2v[0] = __floats2half2_rn(b0 * sc, b1 * sc);                       \
        u.h2v[1] = __floats2half2_rn(b2 * sc, b3 * sc);                       \
        *(float2*)&hw1[(g0 + r) * 64 + j] = u.f2;                             \
    }
    STORE_ROW(0, a00, a01, a02, a03)
    STORE_ROW(1, a10, a11, a12, a13)
    STORE_ROW(2, a20, a21, a22, a23)
    STORE_ROW(3, a30, a31, a32, a33)
#undef STORE_ROW
}

// ---------------- layer-1 gather (pre-scaled, shuffle-free, 8-deep MLP) ----
// h2[d][c] = relu(b1[c] + dinv[d] * (sum_e hw1'[s] + hw1'[d]))
__global__ __launch_bounds__(256) void k_gather1(const int* __restrict__ off,
                                                 const int* __restrict__ csr,
                                                 const float* __restrict__ dinv,
                                                 const __half* __restrict__ hw,
                                                 const float* __restrict__ b1,
                                                 __half* __restrict__ h2out) {
    int lane = threadIdx.x & 63;
    int wave = threadIdx.x >> 6;
    int d = blockIdx.x * 4 + wave;             // grid = NN/4 exactly
    int start = (d == 0) ? 0 : off[d - 1];
    int end = off[d];
    start = __builtin_amdgcn_readfirstlane(start);   // force SGPR bounds ->
    end   = __builtin_amdgcn_readfirstlane(end);     // scalar csr loads
    float dd = dinv[d];
    float hself = __half2float(hw[d * 64 + lane]);   // hoisted: overlaps loop
    float acc0 = 0.0f, acc1 = 0.0f, acc2 = 0.0f, acc3 = 0.0f;
    int e = start;
    for (; e + 7 < end; e += 8) {              // 8 outstanding gathers
        int s0 = csr[e],     s1 = csr[e + 1];
        int s2 = csr[e + 2], s3 = csr[e + 3];
        int s4 = csr[e + 4], s5 = csr[e + 5];
        int s6 = csr[e + 6], s7 = csr[e + 7];
        float g0 = __half2float(hw[s0 * 64 + lane]);
        float g1 = __half2float(hw[s1 * 64 + lane]);
        float g2 = __half2float(hw[s2 * 64 + lane]);
        float g3 = __half2float(hw[s3 * 64 + lane]);
        float g4 = __half2float(hw[s4 * 64 + lane]);
        float g5 = __half2float(hw[s5 * 64 + lane]);
        float g6 = __half2float(hw[s6 * 64 + lane]);
        float g7 = __half2float(hw[s7 * 64 + lane]);
        acc0 += g0; acc1 += g1; acc2 += g2; acc3 += g3;
        acc0 += g4; acc1 += g5; acc2 += g6; acc3 += g7;
    }
    for (; e < end; ++e)                       // uniform remainder
        acc0 += __half2float(hw[csr[e] * 64 + lane]);
    float v = fmaxf(b1[lane] + dd * (((acc0 + acc1) + (acc2 + acc3)) + hself), 0.0f);
    h2out[d * 64 + lane] = __float2half_rn(v);
}

// ---------------- hw2' = dinv * (h2 @ W2)  (64 -> 32), fp16 in/out ---------
__global__ __launch_bounds__(256) void k_hw2(const __half* __restrict__ h2,
                                             const float* __restrict__ W2,
                                             const float* __restrict__ dinv,
                                             __half* __restrict__ hw2) {
    __shared__ float sh[TM2 * 65];  // [node][feat], stride 65 (pad)
    __shared__ float sw[64 * 32];   // [k][j]
    int tid = threadIdx.x;
    for (int t = tid; t < 64 * 32; t += 256) sw[t] = W2[t];
    int nb = blockIdx.x * TM2;
    for (int i = tid; i < TM2 * 64; i += 256) {      // coalesced 2B loads
        int node = i >> 6, ch = i & 63;
        int g = nb + node;
        sh[node * 65 + ch] = (g < NN) ? __half2float(h2[g * 64 + ch]) : 0.0f;
    }
    __syncthreads();
    int j  = (tid & 7) * 4;         // output channel base (32 ch -> 8 groups)
    int nl = (tid >> 3) * 4;        // local node base (128 nodes -> 32 groups)
    float a00=0,a01=0,a02=0,a03=0, a10=0,a11=0,a12=0,a13=0;
    float a20=0,a21=0,a22=0,a23=0, a30=0,a31=0,a32=0,a33=0;
#pragma unroll 4
    for (int k = 0; k < 64; ++k) {
        float4 wv = *(const float4*)&sw[k * 32 + j];
        float h0 = sh[(nl + 0) * 65 + k];
        float h1 = sh[(nl + 1) * 65 + k];
        float h2v = sh[(nl + 2) * 65 + k];
        float h3 = sh[(nl + 3) * 65 + k];
        a00 += h0 * wv.x;  a01 += h0 * wv.y;  a02 += h0 * wv.z;  a03 += h0 * wv.w;
        a10 += h1 * wv.x;  a11 += h1 * wv.y;  a12 += h1 * wv.z;  a13 += h1 * wv.w;
        a20 += h2v * wv.x; a21 += h2v * wv.y; a22 += h2v * wv.z; a23 += h2v * wv.w;
        a30 += h3 * wv.x;  a31 += h3 * wv.y;  a32 += h3 * wv.z;  a33 += h3 * wv.w;
    }
    int g0 = nb + nl;
    union { __half2 h2v2[2]; float2 f2; } u;
#define STORE_ROW(r, b0, b1, b2, b3)                                          \
    if (g0 + r < NN) {                                                        \
        float sc = dinv[g0 + r];                                              \
        u.h2v2[0] = __floats2half2_rn(b0 * sc, b1 * sc);                      \
        u.h2v2[1] = __floats2half2_rn(b2 * sc, b3 * sc);                      \
        *(float2*)&hw2[(g0 + r) * 32 + j] = u.f2;                             \
    }
    STORE_ROW(0, a00, a01, a02, a03)
    STORE_ROW(1, a10, a11, a12, a13)
    STORE_ROW(2, a20, a21, a22, a23)
    STORE_ROW(3, a30, a31, a32, a33)
#undef STORE_ROW
}

// ---------------- layer-2 gather (C=32, pre-scaled, 8 outstanding) ---------
// z[d][j] = b2[j] + dinv[d] * (sum_e hw2'[s] + hw2'[d])
__global__ __launch_bounds__(256) void k_gather2(const int* __restrict__ off,
                                                 const int* __restrict__ csr,
                                                 const float* __restrict__ dinv,
                                                 const __half* __restrict__ hw,
                                                 const float* __restrict__ b2,
                                                 float* __restrict__ outz) {
    int lane = threadIdx.x & 63;
    int half = lane >> 5;
    int j = lane & 31;
    int wave = threadIdx.x >> 6;
    int d = blockIdx.x * 4 + wave;             // grid = NN/4 exactly
    int start = (d == 0) ? 0 : off[d - 1];
    int end = off[d];
    start = __builtin_amdgcn_readfirstlane(start);
    end   = __builtin_amdgcn_readfirstlane(end);
    float dd = dinv[d];
    float hself = __half2float(hw[d * 32 + j]);      // hoisted
    float accA = 0.0f, accB = 0.0f, accC = 0.0f, accD = 0.0f;
    int e = start;
    for (; e + 7 < end; e += 8) {              // 4 gathers per half in flight
        int sA = csr[e + half];
        int sB = csr[e + half + 2];
        int sC = csr[e + half + 4];
        int sD = csr[e + half + 6];
        accA += __half2float(hw[sA * 32 + j]);
        accB += __half2float(hw[sB * 32 + j]);
        accC += __half2float(hw[sC * 32 + j]);
        accD += __half2float(hw[sD * 32 + j]);
    }
    for (int ee = e + half; ee < end; ee += 2)       // divergent-safe tail
        accA += __half2float(hw[csr[ee] * 32 + j]);
    float acc = (accA + accB) + (accC + accD);
    acc += __shfl(acc, lane ^ 32, 64);         // combine halves (full exec)
    if (half == 0)
        outz[d * 32 + j] = b2[j] + dd * (acc + hself);
}

// ---------------- link prediction head: 16 lanes per edge ------------------
__global__ __launch_bounds__(256) void k_linkpred(const int* __restrict__ sidx,
                                                  const int* __restrict__ didx,
                                                  const float* __restrict__ z,
                                                  const float* __restrict__ Wl,
                                                  const float* __restrict__ bl,
                                                  float* __restrict__ pred) {
    int t = blockIdx.x * blockDim.x + threadIdx.x;
    int e = t >> 4;                            // edge per 16-lane group
    int l = t & 15;
    int s = sidx[e], d = didx[e];              // broadcast within group
    float2 zs = *(const float2*)&z[s * 32 + 2 * l];   // 128B coalesced/row
    float2 zd = *(const float2*)&z[d * 32 + 2 * l];
    float2 ws = *(const float2*)&Wl[2 * l];
    float2 wd = *(const float2*)&Wl[32 + 2 * l];
    float v = zs.x * ws.x + zs.y * ws.y + zd.x * wd.x + zd.y * wd.y;
    v += __shfl_xor(v, 1, 64);                 // reduce within 16-lane group
    v += __shfl_xor(v, 2, 64);
    v += __shfl_xor(v, 4, 64);
    v += __shfl_xor(v, 8, 64);
    if (l == 0) pred[e] = v + bl[0];
}

extern "C" void kernel_launch(void* const* d_in, const int* in_sizes, int n_in,
                              void* d_out, int out_size, void* d_ws, size_t ws_size,
                              hipStream_t stream) {
    const float* x    = (const float*)d_in[0];
    const float* pos  = (const float*)d_in[1];
    const float* W1   = (const float*)d_in[2];
    const float* b1   = (const float*)d_in[3];
    const float* W2   = (const float*)d_in[4];
    const float* b2   = (const float*)d_in[5];
    const float* Wl   = (const float*)d_in[6];
    const float* bl   = (const float*)d_in[7];
    const int*   ei   = (const int*)d_in[8];   // [2, NE]
    const int*   eli  = (const int*)d_in[9];   // [2, NEL]
    const int* src  = ei;
    const int* dst  = ei + NE;
    const int* lsrc = eli;
    const int* ldst = eli + NEL;

    float* out_z    = (float*)d_out;            // [NN, 32]
    float* out_pred = (float*)d_out + NN * 32;  // [NEL]

    // workspace: dinv[NN]f | off[NN]i | gcur[NBUCK] | bbase[NBUCK] | csr[NE]
    //            | hw1'[NN*64]h (aliases part[NBUCK*CAPB]i, dead after build)
    //            | h2[NN*64]h | hw2'[NN*32]h          ~= 39.2 MB (R11-proven)
    float*  dinv  = (float*)d_ws;
    int*    off   = (int*)(dinv + NN);
    int*    gcur  = off + NN;
    int*    bbase = gcur + NBUCK;
    int*    csr   = bbase + NBUCK;
    __half* hw1   = (__half*)(csr + NE);
    int*    part  = (int*)hw1;                  // 8.03 MB <= hw1's 12.8 MB
    __half* h2    = hw1 + NN * 64;
    __half* hw2   = h2 + NN * 64;

    // 1) CSR build: partition -> bucket scan -> per-bucket LDS sort (+dinv)
    k_initcur<<<1, 256, 0, stream>>>(gcur);
    k_part<<<(NE + TPE - 1) / TPE, 256, 0, stream>>>(src, dst, gcur, part);
    k_bscan2<<<1, 256, 0, stream>>>(gcur, bbase);
    k_build<<<NBUCK, 256, 0, stream>>>(gcur, bbase, part, csr, off, dinv);

    // 2) hw1' = dinv * ([x|pos] @ W1), fp16  (overwrites part — now dead)
    k_hw1<<<(NN + TM - 1) / TM, 256, 0, stream>>>(x, pos, W1, dinv, hw1);

    // 3) layer-1 gather + bias + relu -> h2 (fp16), shuffle-free, 8-deep
    k_gather1<<<NN / 4, 256, 0, stream>>>(off, csr, dinv, hw1, b1, h2);

    // 4) hw2' = dinv * (h2 @ W2), fp16
    k_hw2<<<(NN + TM2 - 1) / TM2, 256, 0, stream>>>(h2, W2, dinv, hw2);

    // 5) layer-2 gather + bias -> z (fp32 out)
    k_gather2<<<NN / 4, 256, 0, stream>>>(off, csr, dinv, hw2, b2, out_z);

    // 6) link prediction (16 lanes/edge, grid exact)
    k_linkpred<<<NEL * 16 / 256, 256, 0, stream>>>(lsrc, ldst, out_z, Wl, bl, out_pred);
}